// Round 1
// baseline (202.762 us; speedup 1.0000x reference)
//
#include <hip/hip_runtime.h>

#define H_ 128
#define W_ 160
#define C_ 32
#define D_ 64
#define HW_ (H_*W_)          // 20480
#define DHW_ (D_*HW_)        // 1310720
#define NVIEW 5

// var/conv tile
#define TY 16
#define TX 16
#define HY 18                // TY+2
#define HXP 19               // TX+2 padded to 19 (one dead column)
#define NP_ (HY*HXP)         // 342
#define PSTR 343             // odd -> conflict-free per-channel stride

// ws layout (floats)
#define FEATT_SZ (NVIEW*HW_*C_)      // 3,276,800
#define MATS_OFF FEATT_SZ
#define A_OFF (MATS_OFF + 64)
// total floats = A_OFF + 3*DHW_  = 7,209,024  (~28.8 MB)

// ---------------------------------------------------------------- setup mats
__global__ void k_setup_mats(const float* __restrict__ proj,
                             float* __restrict__ mats)
{
    if (threadIdx.x != 0 || blockIdx.x != 0) return;
    // fused[v] top 3x4 = K[:3,:3] @ E[:3,:4]; row3 = [0,0,0,1]
    double F[5][12];
    for (int v = 0; v < 5; ++v) {
        const float* E = proj + v*32;        // [4][4]
        const float* K = proj + v*32 + 16;   // [4][4]
        for (int i = 0; i < 3; ++i)
            for (int j = 0; j < 4; ++j) {
                double s = 0.0;
                for (int k = 0; k < 3; ++k)
                    s += (double)K[i*4+k] * (double)E[k*4+j];
                F[v][i*4+j] = s;
            }
    }
    const double m00=F[0][0], m01=F[0][1], m02=F[0][2],  t0x=F[0][3];
    const double m10=F[0][4], m11=F[0][5], m12=F[0][6],  t0y=F[0][7];
    const double m20=F[0][8], m21=F[0][9], m22=F[0][10], t0z=F[0][11];
    const double det = m00*(m11*m22-m12*m21) - m01*(m10*m22-m12*m20)
                     + m02*(m10*m21-m11*m20);
    const double id = 1.0/det;
    double inv[9];
    inv[0] = (m11*m22-m12*m21)*id; inv[1] = (m02*m21-m01*m22)*id; inv[2] = (m01*m12-m02*m11)*id;
    inv[3] = (m12*m20-m10*m22)*id; inv[4] = (m00*m22-m02*m20)*id; inv[5] = (m02*m10-m00*m12)*id;
    inv[6] = (m10*m21-m11*m20)*id; inv[7] = (m01*m20-m00*m21)*id; inv[8] = (m00*m11-m01*m10)*id;
    double it[3];
    it[0] = -(inv[0]*t0x + inv[1]*t0y + inv[2]*t0z);
    it[1] = -(inv[3]*t0x + inv[4]*t0y + inv[5]*t0z);
    it[2] = -(inv[6]*t0x + inv[7]*t0y + inv[8]*t0z);
    for (int v = 1; v < 5; ++v) {
        float* o = mats + (v-1)*12;
        for (int r = 0; r < 3; ++r) {
            for (int c = 0; c < 3; ++c) {
                double s = 0.0;
                for (int k = 0; k < 3; ++k) s += F[v][r*4+k]*inv[k*3+c];
                o[r*3+c] = (float)s;
            }
            double tr = F[v][r*4+3] + F[v][r*4+0]*it[0]
                      + F[v][r*4+1]*it[1] + F[v][r*4+2]*it[2];
            o[9+r] = (float)tr;
        }
    }
}

// ---------------------------------------------------------------- transpose (C,H,W) -> (HW, C)
__global__ void k_transpose(const float* __restrict__ f, float* __restrict__ ft)
{
    __shared__ float tile[C_][65];
    const int pix0 = blockIdx.x * 64;
    const int tid = threadIdx.x;
    const int p  = tid & 63;
    const int ci = (tid >> 6) * 8;
#pragma unroll
    for (int i = 0; i < 8; ++i)
        tile[ci + i][p] = f[(size_t)(ci + i)*HW_ + pix0 + p];
    __syncthreads();
    const int c2 = tid & 31, pg = tid >> 5;
#pragma unroll
    for (int i = 0; i < 8; ++i) {
        int p2 = pg + i*8;
        ft[(size_t)(pix0 + p2)*C_ + c2] = tile[c2][p2];
    }
}

// ---------------------------------------------------------------- variance slice + spatial conv
__global__ __launch_bounds__(256, 3) void k_var_conv(
    const float* __restrict__ featT, const float* __restrict__ mats,
    const float* __restrict__ depthv, const float* __restrict__ convw,
    float* __restrict__ A)
{
    __shared__ float var_lds[C_ * PSTR];   // [c][p], 43.9 KB
    const int x0 = blockIdx.x * TX;
    const int y0 = blockIdx.y * TY;
    const int bd = blockIdx.z;
    const float depth = depthv[bd];

    // fold depth into projection: pxyz_i = (m_i0*d)*gx + (m_i1*d)*gy + (m_i2*d + t_i)
    float cf[4][9];
#pragma unroll
    for (int v = 0; v < 4; ++v) {
        const float* mm = mats + v*12;
#pragma unroll
        for (int r = 0; r < 3; ++r) {
            cf[v][r*3+0] = mm[r*3+0]*depth;
            cf[v][r*3+1] = mm[r*3+1]*depth;
            cf[v][r*3+2] = fmaf(mm[r*3+2], depth, mm[9+r]);
        }
    }

    const int lane_c = (threadIdx.x & 7) * 4;   // channel quad base
    const int pg     = threadIdx.x >> 3;        // 0..31 position group

    for (int p = pg; p < NP_; p += 32) {
        const int hy = p / HXP;
        const int hx = p - hy*HXP;
        const int gy = y0 - 1 + hy;
        const int gx = x0 - 1 + hx;
        float var[4] = {0.f, 0.f, 0.f, 0.f};
        if (hx < (TX+2) && (unsigned)gy < (unsigned)H_ && (unsigned)gx < (unsigned)W_) {
            const float fgx = (float)gx, fgy = (float)gy;
            const int pix = gy*W_ + gx;
            float s[4], q[4];
            {
                float4 t = *reinterpret_cast<const float4*>(featT + (size_t)pix*C_ + lane_c);
                s[0]=t.x; s[1]=t.y; s[2]=t.z; s[3]=t.w;
#pragma unroll
                for (int k = 0; k < 4; ++k) q[k] = s[k]*s[k];
            }
#pragma unroll
            for (int v = 0; v < 4; ++v) {
                const float xx = fmaf(cf[v][0],fgx, fmaf(cf[v][1],fgy, cf[v][2]));
                const float yy = fmaf(cf[v][3],fgx, fmaf(cf[v][4],fgy, cf[v][5]));
                const float zz = fmaf(cf[v][6],fgx, fmaf(cf[v][7],fgy, cf[v][8]));
                const float rz = 1.0f / zz;
                const float px = xx*rz, py = yy*rz;
                const float xf = floorf(px), yf = floorf(py);
                const float wx = px - xf, wy = py - yf;
                const int xi = (int)xf, yi = (int)yf;
                const bool vx0 = (xi >=  0) & (xi <= W_-1);
                const bool vx1 = (xi >= -1) & (xi <= W_-2);
                const bool vy0 = (yi >=  0) & (yi <= H_-1);
                const bool vy1 = (yi >= -1) & (yi <= H_-2);
                const int xc0 = min(max(xi,   0), W_-1);
                const int xc1 = min(max(xi+1, 0), W_-1);
                const int yc0 = min(max(yi,   0), H_-1);
                const int yc1 = min(max(yi+1, 0), H_-1);
                const float ux = 1.f - wx, uy = 1.f - wy;
                const float w00 = (vx0 && vy0) ? ux*uy : 0.f;
                const float w10 = (vx1 && vy0) ? wx*uy : 0.f;
                const float w01 = (vx0 && vy1) ? ux*wy : 0.f;
                const float w11 = (vx1 && vy1) ? wx*wy : 0.f;
                const float* fb = featT + (size_t)(v+1)*HW_*C_ + lane_c;
                const float4 t00 = *reinterpret_cast<const float4*>(fb + (size_t)(yc0*W_+xc0)*C_);
                const float4 t10 = *reinterpret_cast<const float4*>(fb + (size_t)(yc0*W_+xc1)*C_);
                const float4 t01 = *reinterpret_cast<const float4*>(fb + (size_t)(yc1*W_+xc0)*C_);
                const float4 t11 = *reinterpret_cast<const float4*>(fb + (size_t)(yc1*W_+xc1)*C_);
                const float a00[4] = {t00.x,t00.y,t00.z,t00.w};
                const float a10[4] = {t10.x,t10.y,t10.z,t10.w};
                const float a01[4] = {t01.x,t01.y,t01.z,t01.w};
                const float a11[4] = {t11.x,t11.y,t11.z,t11.w};
#pragma unroll
                for (int k = 0; k < 4; ++k) {
                    float wv = fmaf(a00[k],w00, fmaf(a10[k],w10, fmaf(a01[k],w01, a11[k]*w11)));
                    s[k] += wv;
                    q[k] = fmaf(wv, wv, q[k]);
                }
            }
#pragma unroll
            for (int k = 0; k < 4; ++k) {
                const float sm = s[k]*0.2f;
                var[k] = q[k]*0.2f - sm*sm;
            }
        }
#pragma unroll
        for (int k = 0; k < 4; ++k)
            var_lds[(lane_c+k)*PSTR + p] = var[k];
    }
    __syncthreads();

    // spatial 3x3 conv, 3 depth-tap partials A[kd]
    const int tid = threadIdx.x;
    const int oy = tid >> 4;      // 0..15
    const int ox = tid & 15;      // 0..15
    float a0 = 0.f, a1 = 0.f, a2 = 0.f;
#pragma unroll 4
    for (int cc = 0; cc < C_; ++cc) {
        const float* vrow = var_lds + cc*PSTR;
        const float* wc   = convw + cc*27;   // w[c][kd][ky][kx]
#pragma unroll
        for (int ky = 0; ky < 3; ++ky) {
            const int base = (oy+ky)*HXP + ox;
            const float u0 = vrow[base+0];
            const float u1 = vrow[base+1];
            const float u2 = vrow[base+2];
            const float* wk = wc + ky*3;
            a0 = fmaf(u0, wk[0],  fmaf(u1, wk[1],  fmaf(u2, wk[2],  a0)));
            a1 = fmaf(u0, wk[9],  fmaf(u1, wk[10], fmaf(u2, wk[11], a1)));
            a2 = fmaf(u0, wk[18], fmaf(u1, wk[19], fmaf(u2, wk[20], a2)));
        }
    }
    const size_t o = (size_t)bd*HW_ + (size_t)(y0+oy)*W_ + (x0+ox);
    A[o]                    = a0;
    A[(size_t)DHW_ + o]     = a1;
    A[2*(size_t)DHW_ + o]   = a2;
}

// ---------------------------------------------------------------- depth combine + softmax
__global__ void k_softmax(const float* __restrict__ A,
                          const float* __restrict__ conv_b,
                          float* __restrict__ out)
{
    const int pix = blockIdx.x*256 + threadIdx.x;
    const float bs = conv_b[0];
    float cst[D_];
#pragma unroll
    for (int d = 0; d < D_; ++d) {
        float v = A[(size_t)DHW_ + (size_t)d*HW_ + pix];          // A1[d]
        if (d > 0)      v += A[(size_t)(d-1)*HW_ + pix];          // A0[d-1]
        if (d < D_-1)   v += A[2*(size_t)DHW_ + (size_t)(d+1)*HW_ + pix]; // A2[d+1]
        cst[d] = v + bs;
    }
    float m = cst[0];
#pragma unroll
    for (int d = 1; d < D_; ++d) m = fmaxf(m, cst[d]);
    float s = 0.f;
#pragma unroll
    for (int d = 0; d < D_; ++d) { cst[d] = expf(cst[d] - m); s += cst[d]; }
    const float rs = 1.0f / s;
#pragma unroll
    for (int d = 0; d < D_; ++d)
        out[(size_t)d*HW_ + pix] = cst[d]*rs;
}

// ---------------------------------------------------------------- launch
extern "C" void kernel_launch(void* const* d_in, const int* in_sizes, int n_in,
                              void* d_out, int out_size, void* d_ws, size_t ws_size,
                              hipStream_t stream)
{
    const float* proj   = (const float*)d_in[5];
    const float* depth  = (const float*)d_in[6];
    const float* conv_w = (const float*)d_in[8];
    const float* conv_b = (const float*)d_in[9];

    float* ws    = (float*)d_ws;
    float* featT = ws;
    float* mats  = ws + MATS_OFF;
    float* A     = ws + A_OFF;

    k_setup_mats<<<1, 64, 0, stream>>>(proj, mats);
    for (int v = 0; v < 5; ++v)
        k_transpose<<<HW_/64, 256, 0, stream>>>((const float*)d_in[v],
                                                featT + (size_t)v*HW_*C_);
    dim3 g1(W_/TX, H_/TY, D_);   // (10, 8, 64)
    k_var_conv<<<g1, 256, 0, stream>>>(featT, mats, depth, conv_w, A);
    k_softmax<<<HW_/256, 256, 0, stream>>>(A, conv_b, (float*)d_out);
}